// Round 1
// baseline (4069.379 us; speedup 1.0000x reference)
//
#include <hip/hip_runtime.h>
#include <hip/hip_bf16.h>

// Problem constants
#define BB 16
#define LL 1024
#define DD 384
#define FF 1536
#define KK 3
#define T_OUT 10240
#define MAX_DUR 10

// ---------------- weight transpose: (O,I,K) -> (k*I+i)*O + o ----------------
__global__ void transpose_w_k(const float* __restrict__ w, float* __restrict__ wt,
                              int O, int I) {
    int id = blockIdx.x * 256 + threadIdx.x;
    int n = O * I * KK;
    if (id >= n) return;
    int o = id % O;
    int rest = id / O;
    int i = rest % I;
    int k = rest / I;
    wt[id] = w[(o * I + i) * KK + k];
}

// ---------------- conv-as-GEMM: Y[m,n] = relu(sum_kk A[m,kk]*Wt[kk,n] + bias[n])
// A[m, k*Cin+d] = X[b, l+k-1, d] (zero halo), m = b*1024 + l
__global__ __launch_bounds__(256) void gemm_conv_relu(
        const float* __restrict__ X, const float* __restrict__ Wt,
        const float* __restrict__ bias, float* __restrict__ Y,
        int Cin, int Cout) {
    __shared__ float As[16][68];   // padded: store bank-spread, float4-aligned rows
    __shared__ float Bs[16][64];
    const int tid = threadIdx.x;
    const int tx = tid & 15, ty = tid >> 4;
    const int m0 = blockIdx.y * 64;
    const int n0 = blockIdx.x * 64;
    const int b  = m0 >> 10;        // 1024 % 64 == 0: tile within one batch
    const int l0 = m0 & 1023;
    const int arow = tid >> 2, acol = (tid & 3) << 2;
    const int brow = tid >> 4, bcol = (tid & 15) << 2;
    const int Kred = 3 * Cin;

    float acc[4][4] = {};

    for (int kk0 = 0; kk0 < Kred; kk0 += 16) {
        int kseg = (kk0 >= 2 * Cin) ? 2 : ((kk0 >= Cin) ? 1 : 0);
        int d0 = kk0 - kseg * Cin;
        // ---- load A tile (64 rows x 16 cols), transposed into As[k][m]
        {
            int ls = l0 + arow + kseg - 1;
            float4 v = make_float4(0.f, 0.f, 0.f, 0.f);
            if (ls >= 0 && ls < LL) {
                v = *(const float4*)(X + ((size_t)((b << 10) + ls)) * Cin + d0 + acol);
            }
            As[acol + 0][arow] = v.x;
            As[acol + 1][arow] = v.y;
            As[acol + 2][arow] = v.z;
            As[acol + 3][arow] = v.w;
        }
        // ---- load B tile (16 x 64), coalesced
        {
            float4 v = *(const float4*)(Wt + (size_t)(kk0 + brow) * Cout + n0 + bcol);
            *(float4*)&Bs[brow][bcol] = v;
        }
        __syncthreads();
        #pragma unroll
        for (int kki = 0; kki < 16; ++kki) {
            float4 a  = *(const float4*)&As[kki][ty << 2];
            float4 b4 = *(const float4*)&Bs[kki][tx << 2];
            acc[0][0] += a.x * b4.x; acc[0][1] += a.x * b4.y;
            acc[0][2] += a.x * b4.z; acc[0][3] += a.x * b4.w;
            acc[1][0] += a.y * b4.x; acc[1][1] += a.y * b4.y;
            acc[1][2] += a.y * b4.z; acc[1][3] += a.y * b4.w;
            acc[2][0] += a.z * b4.x; acc[2][1] += a.z * b4.y;
            acc[2][2] += a.z * b4.z; acc[2][3] += a.z * b4.w;
            acc[3][0] += a.w * b4.x; acc[3][1] += a.w * b4.y;
            acc[3][2] += a.w * b4.z; acc[3][3] += a.w * b4.w;
        }
        __syncthreads();
    }
    float4 bb = *(const float4*)(bias + n0 + (tx << 2));
    #pragma unroll
    for (int i = 0; i < 4; ++i) {
        int m = m0 + (ty << 2) + i;
        float4 r;
        r.x = fmaxf(acc[i][0] + bb.x, 0.f);
        r.y = fmaxf(acc[i][1] + bb.y, 0.f);
        r.z = fmaxf(acc[i][2] + bb.z, 0.f);
        r.w = fmaxf(acc[i][3] + bb.w, 0.f);
        *(float4*)(Y + (size_t)m * Cout + n0 + (tx << 2)) = r;
    }
}

// ---------------- layernorm (in place), row = 384 floats, 128 threads ------
__global__ __launch_bounds__(128) void ln_inplace(
        float* __restrict__ H, const float* __restrict__ g,
        const float* __restrict__ be) {
    const int row = blockIdx.x;
    float* x = H + (size_t)row * DD;
    const int tid = threadIdx.x;
    float v0 = x[tid], v1 = x[tid + 128], v2 = x[tid + 256];

    __shared__ float sh[2];
    // pass 1: mean
    float s = v0 + v1 + v2;
    #pragma unroll
    for (int o = 32; o > 0; o >>= 1) s += __shfl_down(s, o, 64);
    if ((tid & 63) == 0) sh[tid >> 6] = s;
    __syncthreads();
    float mu = (sh[0] + sh[1]) * (1.f / DD);
    __syncthreads();
    // pass 2: var
    float d0 = v0 - mu, d1 = v1 - mu, d2 = v2 - mu;
    float q = d0 * d0 + d1 * d1 + d2 * d2;
    #pragma unroll
    for (int o = 32; o > 0; o >>= 1) q += __shfl_down(q, o, 64);
    if ((tid & 63) == 0) sh[tid >> 6] = q;
    __syncthreads();
    float var = (sh[0] + sh[1]) * (1.f / DD);
    float rs = rsqrtf(var + 1e-5f);
    x[tid]       = d0 * rs * g[tid]       + be[tid];
    x[tid + 128] = d1 * rs * g[tid + 128] + be[tid + 128];
    x[tid + 256] = d2 * rs * g[tid + 256] + be[tid + 256];
}

// ---------------- layernorm + length predictor -> lns[row] -----------------
__global__ __launch_bounds__(128) void ln_pred(
        const float* __restrict__ H, const float* __restrict__ g,
        const float* __restrict__ be, const float* __restrict__ wl,
        const float* __restrict__ bl, const int* __restrict__ token_lengths,
        int* __restrict__ lns) {
    const int row = blockIdx.x;
    const float* x = H + (size_t)row * DD;
    const int tid = threadIdx.x;
    float v0 = x[tid], v1 = x[tid + 128], v2 = x[tid + 256];

    __shared__ float sh[2];
    float s = v0 + v1 + v2;
    #pragma unroll
    for (int o = 32; o > 0; o >>= 1) s += __shfl_down(s, o, 64);
    if ((tid & 63) == 0) sh[tid >> 6] = s;
    __syncthreads();
    float mu = (sh[0] + sh[1]) * (1.f / DD);
    __syncthreads();
    float d0 = v0 - mu, d1 = v1 - mu, d2 = v2 - mu;
    float q = d0 * d0 + d1 * d1 + d2 * d2;
    #pragma unroll
    for (int o = 32; o > 0; o >>= 1) q += __shfl_down(q, o, 64);
    if ((tid & 63) == 0) sh[tid >> 6] = q;
    __syncthreads();
    float var = (sh[0] + sh[1]) * (1.f / DD);
    float rs = rsqrtf(var + 1e-5f);
    __syncthreads();
    // predictor: dot(norm, wl)
    float p = (d0 * rs * g[tid]       + be[tid])       * wl[tid]
            + (d1 * rs * g[tid + 128] + be[tid + 128]) * wl[tid + 128]
            + (d2 * rs * g[tid + 256] + be[tid + 256]) * wl[tid + 256];
    #pragma unroll
    for (int o = 32; o > 0; o >>= 1) p += __shfl_down(p, o, 64);
    if ((tid & 63) == 0) sh[tid >> 6] = p;
    __syncthreads();
    if (tid == 0) {
        float pred = sh[0] + sh[1] + bl[0];
        float e = expf(pred);           // ALPHA == 1.0
        float r = rintf(e);             // round-half-even, matches jnp.round
        r = fminf(fmaxf(r, 0.f), (float)MAX_DUR);
        int v = (int)r;
        int b = row >> 10, l = row & 1023;
        if (l >= token_lengths[b]) v = 0;
        lns[row] = v;
    }
}

// ---------------- per-batch inclusive cumsum (L=1024) -----------------------
__global__ __launch_bounds__(1024) void cumsum_k(
        const int* __restrict__ lns, int* __restrict__ csum,
        float* __restrict__ totals_out) {
    __shared__ int s[1024];
    const int b = blockIdx.x, tid = threadIdx.x;
    s[tid] = lns[(b << 10) + tid];
    __syncthreads();
    #pragma unroll
    for (int o = 1; o < 1024; o <<= 1) {
        int t = (tid >= o) ? s[tid - o] : 0;
        __syncthreads();
        s[tid] += t;
        __syncthreads();
    }
    csum[(b << 10) + tid] = s[tid];
    if (tid == 1023) totals_out[b] = (float)s[1023];
}

// ---------------- gather: out[b,t,:] = valid ? y[b, idx(t), :] : 0 ----------
__global__ __launch_bounds__(256) void gather_k(
        const float* __restrict__ y, const int* __restrict__ csum,
        float* __restrict__ out) {
    int gid = blockIdx.x * 256 + threadIdx.x;   // B*T_OUT*96 float4 chunks
    int c4 = gid % 96;
    int rest = gid / 96;
    int t = rest % T_OUT;
    int b = rest / T_OUT;
    const int* c = csum + (b << 10);
    int total = c[1023];
    float4 r = make_float4(0.f, 0.f, 0.f, 0.f);
    if (t < total) {
        int lo = 0, hi = 1024;
        while (lo < hi) {               // searchsorted side='right'
            int mid = (lo + hi) >> 1;
            if (c[mid] <= t) lo = mid + 1; else hi = mid;
        }
        int idx = min(lo, LL - 1);
        r = *(const float4*)(y + ((size_t)((b << 10) + idx)) * DD + (c4 << 2));
    }
    *(float4*)(out + ((size_t)b * T_OUT + t) * DD + (c4 << 2)) = r;
}

// ---------------- host side --------------------------------------------------
extern "C" void kernel_launch(void* const* d_in, const int* in_sizes, int n_in,
                              void* d_out, int out_size, void* d_ws, size_t ws_size,
                              hipStream_t stream) {
    const float* y   = (const float*)d_in[0];
    const int*   tok = (const int*)d_in[1];
    const float* w1a = (const float*)d_in[2];
    const float* b1a = (const float*)d_in[3];
    const float* w1b = (const float*)d_in[4];
    const float* b1b = (const float*)d_in[5];
    const float* g1  = (const float*)d_in[6];
    const float* be1 = (const float*)d_in[7];
    const float* w2a = (const float*)d_in[8];
    const float* b2a = (const float*)d_in[9];
    const float* w2b = (const float*)d_in[10];
    const float* b2b = (const float*)d_in[11];
    const float* g2  = (const float*)d_in[12];
    const float* be2 = (const float*)d_in[13];
    const float* wl  = (const float*)d_in[14];
    const float* bl  = (const float*)d_in[15];

    float* out = (float*)d_out;

    // workspace layout (floats)
    const size_t WSZ = (size_t)KK * DD * FF;           // 1,769,472
    float* wt1a = (float*)d_ws;
    float* wt1b = wt1a + WSZ;
    float* wt2a = wt1b + WSZ;
    float* wt2b = wt2a + WSZ;
    float* hBig   = wt2b + WSZ;                         // 16384*1536
    float* hSmall = hBig + (size_t)BB * LL * FF;        // 16384*384
    int*   lns  = (int*)(hSmall + (size_t)BB * LL * DD);
    int*   csum = lns + BB * LL;

    const int M = BB * LL;                              // 16384

    // 1) weight transposes
    {
        int n = FF * DD * KK;
        transpose_w_k<<<(n + 255) / 256, 256, 0, stream>>>(w1a, wt1a, FF, DD);
        transpose_w_k<<<(n + 255) / 256, 256, 0, stream>>>(w1b, wt1b, DD, FF);
        transpose_w_k<<<(n + 255) / 256, 256, 0, stream>>>(w2a, wt2a, FF, DD);
        transpose_w_k<<<(n + 255) / 256, 256, 0, stream>>>(w2b, wt2b, DD, FF);
    }
    // 2) block 1
    gemm_conv_relu<<<dim3(FF / 64, M / 64), 256, 0, stream>>>(y,      wt1a, b1a, hBig,   DD, FF);
    gemm_conv_relu<<<dim3(DD / 64, M / 64), 256, 0, stream>>>(hBig,   wt1b, b1b, hSmall, FF, DD);
    ln_inplace<<<M, 128, 0, stream>>>(hSmall, g1, be1);
    // 3) block 2
    gemm_conv_relu<<<dim3(FF / 64, M / 64), 256, 0, stream>>>(hSmall, wt2a, b2a, hBig,   DD, FF);
    gemm_conv_relu<<<dim3(DD / 64, M / 64), 256, 0, stream>>>(hBig,   wt2b, b2b, hSmall, FF, DD);
    // 4) predictor + cumsum
    ln_pred<<<M, 128, 0, stream>>>(hSmall, g2, be2, wl, bl, tok, lns);
    cumsum_k<<<BB, 1024, 0, stream>>>(lns, csum, out + (size_t)BB * T_OUT * DD);
    // 5) gather/expand
    {
        long long n = (long long)BB * T_OUT * 96;
        gather_k<<<(int)((n + 255) / 256), 256, 0, stream>>>(y, csum, out);
    }
}

// Round 2
// 1223.854 us; speedup vs baseline: 3.3251x; 3.3251x over previous
//
#include <hip/hip_runtime.h>
#include <hip/hip_bf16.h>

// Problem constants
#define BB 16
#define LL 1024
#define DD 384
#define FF 1536
#define KK 3
#define T_OUT 10240
#define MAX_DUR 10

#define PADL 1026                 // per-batch padded rows: [0]=zero, [1..1024]=data, [1025]=zero
#define LO_SCALE 2048.0f          // 2^11: keeps lo parts out of fp16-denormal range
#define LO_INV   4.8828125e-4f    // 2^-11

typedef _Float16 f16x8 __attribute__((ext_vector_type(8)));
typedef float    f32x4 __attribute__((ext_vector_type(4)));

__device__ __forceinline__ void gll16(const void* g, void* l) {
    __builtin_amdgcn_global_load_lds(
        (const __attribute__((address_space(1))) void*)g,
        (__attribute__((address_space(3))) void*)l, 16, 0, 0);
}

__device__ __forceinline__ void split_write(float v, _Float16* hi, _Float16* lo, size_t off) {
    _Float16 h = (_Float16)v;
    hi[off] = h;
    lo[off] = (_Float16)((v - (float)h) * LO_SCALE);
}

__device__ __forceinline__ float split_read(const _Float16* hi, const _Float16* lo, size_t off) {
    return (float)hi[off] + (float)lo[off] * LO_INV;
}

// ---------------- weight transpose+split: (O,I,3) -> [o][k*I+i] hi/lo -------
__global__ void wsplit_k(const float* __restrict__ w, _Float16* __restrict__ hi,
                         _Float16* __restrict__ lo, int O, int I) {
    int id = blockIdx.x * 256 + threadIdx.x;
    int n = O * I * 3;
    if (id >= n) return;
    int o = id / (3 * I);
    int rem = id - o * 3 * I;
    int k = rem / I;
    int i = rem - k * I;
    float v = w[(o * I + i) * 3 + k];
    split_write(v, hi, lo, id);
}

// ---------------- y split into padded hi/lo layout ---------------------------
__global__ void ysplit_k(const float* __restrict__ y, _Float16* __restrict__ hi,
                         _Float16* __restrict__ lo) {
    int id = blockIdx.x * 256 + threadIdx.x;     // BB*PADL*DD
    if (id >= BB * PADL * DD) return;
    int d = id % DD;
    int r = id / DD;
    int b = r / PADL;
    int lr = r - b * PADL;
    float v = 0.f;
    if (lr >= 1 && lr <= LL) v = y[((size_t)(b << 10) + (lr - 1)) * DD + d];
    split_write(v, hi, lo, id);
}

// ---------------- zero the halo pad rows of a padded split buffer ------------
__global__ void padzero_k(_Float16* __restrict__ hi, _Float16* __restrict__ lo, int width) {
    int id = blockIdx.x * 256 + threadIdx.x;     // BB*2*width
    if (id >= BB * 2 * width) return;
    int b = id / (2 * width);
    int rem = id - b * 2 * width;
    int row = (rem / width) ? (PADL - 1) : 0;
    int c = rem % width;
    size_t off = (size_t)(b * PADL + row) * width + c;
    hi[off] = (_Float16)0.f;
    lo[off] = (_Float16)0.f;
}

// ---------------- split-fp16 MFMA conv-GEMM ----------------------------------
// C[m][n] = relu( sum_kk A[m][kk] * W2[n][kk] + bias[n] ),  kk = kseg*Cin + d
// A rows come from the padded split activation buffer (halo via row offset).
// W2 layout: [n][kk] (k-contiguous) so B tiles stage contiguously.
// acc  = Ahi*Bhi ; accC = Ahi*Blo' + Alo'*Bhi (lo' = lo*2^11); v = acc + accC*2^-11.
// LDS layout per tile (per component, 8 KB): 64 super-rows (pairs of m/n rows)
// of 8 16B slots; phys slot = ((row&1)*4 + k8) ^ (superrow & 7)  -- this is
// both contiguous for global_load_lds (base + lane*16) and 2-way (free) on
// ds_read_b128 fragment reads.
__global__ __launch_bounds__(256, 2) void gemm_split(
        const _Float16* __restrict__ Ahi, const _Float16* __restrict__ Alo,
        const _Float16* __restrict__ Whi, const _Float16* __restrict__ Wlo,
        const float* __restrict__ bias,
        _Float16* __restrict__ Ohi, _Float16* __restrict__ Olo,
        int Cin, int Cout, int Ktot, int tilesPerSeg) {
    __shared__ _Float16 lds_h[16384];   // 32 KB: Ahi 0 | Alo 4096 | Bhi 8192 | Blo 12288
    const int tid = threadIdx.x;
    const int lane = tid & 63;
    const int w = tid >> 6;
    const int lm = lane & 15, lq = lane >> 4;
    const int m0 = blockIdx.y * 128;
    const int n0 = blockIdx.x * 128;
    const int b = m0 >> 10;
    const int l0 = m0 & 1023;
    const int rowBase = b * PADL + l0;           // + m + kseg = padded source row
    const int wm = (w >> 1) * 64, wn = (w & 1) * 64;

    f32x4 accM[4][4], accC[4][4];
    const f32x4 zz = {0.f, 0.f, 0.f, 0.f};
    #pragma unroll
    for (int i = 0; i < 4; ++i)
        #pragma unroll
        for (int j = 0; j < 4; ++j) { accM[i][j] = zz; accC[i][j] = zz; }

    const int nKT = Ktot >> 5;
    for (int kt = 0; kt < nKT; ++kt) {
        int kseg = kt / tilesPerSeg;
        int d0 = (kt - kseg * tilesPerSeg) << 5;
        #pragma unroll
        for (int it = 0; it < 2; ++it) {
            int s = (w * 2 + it) * 64 + lane;    // 16B-slot index 0..511
            int p = s >> 3, sl = s & 7;
            int t = sl ^ (p & 7);
            int m = p * 2 + (t >> 2);
            int k8 = t & 3;
            size_t aoff = (size_t)(rowBase + m + kseg) * Cin + d0 + k8 * 8;
            size_t boff = (size_t)(n0 + m) * Ktot + (kt << 5) + k8 * 8;
            _Float16* lbase = lds_h + (size_t)(w * 2 + it) * 512;
            gll16(Ahi + aoff, lbase);
            gll16(Alo + aoff, lbase + 4096);
            gll16(Whi + boff, lbase + 8192);
            gll16(Wlo + boff, lbase + 12288);
        }
        __syncthreads();
        f16x8 aH[4], aL[4], bH[4], bL[4];
        #pragma unroll
        for (int i = 0; i < 4; ++i) {
            int m = wm + i * 16 + lm;
            int p = m >> 1;
            int sl = (((m & 1) << 2) | lq) ^ (p & 7);
            int off = p * 64 + sl * 8;
            aH[i] = *(const f16x8*)(lds_h + off);
            aL[i] = *(const f16x8*)(lds_h + 4096 + off);
            int n = wn + i * 16 + lm;
            int pn = n >> 1;
            int sln = (((n & 1) << 2) | lq) ^ (pn & 7);
            int offn = pn * 64 + sln * 8;
            bH[i] = *(const f16x8*)(lds_h + 8192 + offn);
            bL[i] = *(const f16x8*)(lds_h + 12288 + offn);
        }
        #pragma unroll
        for (int i = 0; i < 4; ++i)
            #pragma unroll
            for (int j = 0; j < 4; ++j) {
                accM[i][j] = __builtin_amdgcn_mfma_f32_16x16x32_f16(aH[i], bH[j], accM[i][j], 0, 0, 0);
                accC[i][j] = __builtin_amdgcn_mfma_f32_16x16x32_f16(aH[i], bL[j], accC[i][j], 0, 0, 0);
                accC[i][j] = __builtin_amdgcn_mfma_f32_16x16x32_f16(aL[i], bH[j], accC[i][j], 0, 0, 0);
            }
        __syncthreads();
    }
    // epilogue: bias + relu + re-split to padded hi/lo output
    #pragma unroll
    for (int i = 0; i < 4; ++i)
        #pragma unroll
        for (int j = 0; j < 4; ++j) {
            int n_g = n0 + wn + j * 16 + lm;
            float bv = bias[n_g];
            #pragma unroll
            for (int r = 0; r < 4; ++r) {
                int l = l0 + wm + i * 16 + lq * 4 + r;
                float v = accM[i][j][r] + accC[i][j][r] * LO_INV + bv;
                v = fmaxf(v, 0.f);
                size_t off = (size_t)(b * PADL + 1 + l) * Cout + n_g;
                split_write(v, Ohi, Olo, off);
            }
        }
}

// ---------------- layernorm in place on split buffer (width 384) -------------
__global__ __launch_bounds__(128) void ln_split_k(
        _Float16* __restrict__ hi, _Float16* __restrict__ lo,
        const float* __restrict__ g, const float* __restrict__ be) {
    const int row = blockIdx.x;
    const int b = row >> 10, l = row & 1023;
    const size_t base = (size_t)(b * PADL + 1 + l) * DD;
    const int tid = threadIdx.x;
    float v0 = split_read(hi, lo, base + tid);
    float v1 = split_read(hi, lo, base + tid + 128);
    float v2 = split_read(hi, lo, base + tid + 256);

    __shared__ float sh[2];
    float s = v0 + v1 + v2;
    #pragma unroll
    for (int o = 32; o > 0; o >>= 1) s += __shfl_down(s, o, 64);
    if ((tid & 63) == 0) sh[tid >> 6] = s;
    __syncthreads();
    float mu = (sh[0] + sh[1]) * (1.f / DD);
    __syncthreads();
    float d0 = v0 - mu, d1 = v1 - mu, d2 = v2 - mu;
    float q = d0 * d0 + d1 * d1 + d2 * d2;
    #pragma unroll
    for (int o = 32; o > 0; o >>= 1) q += __shfl_down(q, o, 64);
    if ((tid & 63) == 0) sh[tid >> 6] = q;
    __syncthreads();
    float var = (sh[0] + sh[1]) * (1.f / DD);
    float rs = rsqrtf(var + 1e-5f);
    split_write(d0 * rs * g[tid] + be[tid], hi, lo, base + tid);
    split_write(d1 * rs * g[tid + 128] + be[tid + 128], hi, lo, base + tid + 128);
    split_write(d2 * rs * g[tid + 256] + be[tid + 256], hi, lo, base + tid + 256);
}

// ---------------- layernorm + length predictor on split buffer ---------------
__global__ __launch_bounds__(128) void ln_pred_split_k(
        const _Float16* __restrict__ hi, const _Float16* __restrict__ lo,
        const float* __restrict__ g, const float* __restrict__ be,
        const float* __restrict__ wl, const float* __restrict__ bl,
        const int* __restrict__ token_lengths, int* __restrict__ lns) {
    const int row = blockIdx.x;
    const int b = row >> 10, l = row & 1023;
    const size_t base = (size_t)(b * PADL + 1 + l) * DD;
    const int tid = threadIdx.x;
    float v0 = split_read(hi, lo, base + tid);
    float v1 = split_read(hi, lo, base + tid + 128);
    float v2 = split_read(hi, lo, base + tid + 256);

    __shared__ float sh[2];
    float s = v0 + v1 + v2;
    #pragma unroll
    for (int o = 32; o > 0; o >>= 1) s += __shfl_down(s, o, 64);
    if ((tid & 63) == 0) sh[tid >> 6] = s;
    __syncthreads();
    float mu = (sh[0] + sh[1]) * (1.f / DD);
    __syncthreads();
    float d0 = v0 - mu, d1 = v1 - mu, d2 = v2 - mu;
    float q = d0 * d0 + d1 * d1 + d2 * d2;
    #pragma unroll
    for (int o = 32; o > 0; o >>= 1) q += __shfl_down(q, o, 64);
    if ((tid & 63) == 0) sh[tid >> 6] = q;
    __syncthreads();
    float var = (sh[0] + sh[1]) * (1.f / DD);
    float rs = rsqrtf(var + 1e-5f);
    __syncthreads();
    float p = (d0 * rs * g[tid]       + be[tid])       * wl[tid]
            + (d1 * rs * g[tid + 128] + be[tid + 128]) * wl[tid + 128]
            + (d2 * rs * g[tid + 256] + be[tid + 256]) * wl[tid + 256];
    #pragma unroll
    for (int o = 32; o > 0; o >>= 1) p += __shfl_down(p, o, 64);
    if ((tid & 63) == 0) sh[tid >> 6] = p;
    __syncthreads();
    if (tid == 0) {
        float pred = sh[0] + sh[1] + bl[0];
        float e = expf(pred);           // ALPHA == 1.0
        float r = rintf(e);             // round-half-even, matches jnp.round
        r = fminf(fmaxf(r, 0.f), (float)MAX_DUR);
        int v = (int)r;
        if (l >= token_lengths[b]) v = 0;
        lns[row] = v;
    }
}

// ---------------- per-batch inclusive cumsum (L=1024) ------------------------
__global__ __launch_bounds__(1024) void cumsum_k(
        const int* __restrict__ lns, int* __restrict__ csum,
        float* __restrict__ totals_out) {
    __shared__ int s[1024];
    const int b = blockIdx.x, tid = threadIdx.x;
    s[tid] = lns[(b << 10) + tid];
    __syncthreads();
    #pragma unroll
    for (int o = 1; o < 1024; o <<= 1) {
        int t = (tid >= o) ? s[tid - o] : 0;
        __syncthreads();
        s[tid] += t;
        __syncthreads();
    }
    csum[(b << 10) + tid] = s[tid];
    if (tid == 1023) totals_out[b] = (float)s[1023];
}

// ---------------- gather: out[b,t,:] = valid ? y[b, idx(t), :] : 0 -----------
__global__ __launch_bounds__(256) void gather_k(
        const float* __restrict__ y, const int* __restrict__ csum,
        float* __restrict__ out) {
    int gid = blockIdx.x * 256 + threadIdx.x;   // B*T_OUT*96 float4 chunks
    int c4 = gid % 96;
    int rest = gid / 96;
    int t = rest % T_OUT;
    int b = rest / T_OUT;
    const int* c = csum + (b << 10);
    int total = c[1023];
    float4 r = make_float4(0.f, 0.f, 0.f, 0.f);
    if (t < total) {
        int lo = 0, hi = 1024;
        while (lo < hi) {               // searchsorted side='right'
            int mid = (lo + hi) >> 1;
            if (c[mid] <= t) lo = mid + 1; else hi = mid;
        }
        int idx = min(lo, LL - 1);
        r = *(const float4*)(y + ((size_t)((b << 10) + idx)) * DD + (c4 << 2));
    }
    *(float4*)(out + ((size_t)b * T_OUT + t) * DD + (c4 << 2)) = r;
}

// ---------------- host side --------------------------------------------------
extern "C" void kernel_launch(void* const* d_in, const int* in_sizes, int n_in,
                              void* d_out, int out_size, void* d_ws, size_t ws_size,
                              hipStream_t stream) {
    const float* y   = (const float*)d_in[0];
    const int*   tok = (const int*)d_in[1];
    const float* w1a = (const float*)d_in[2];
    const float* b1a = (const float*)d_in[3];
    const float* w1b = (const float*)d_in[4];
    const float* b1b = (const float*)d_in[5];
    const float* g1  = (const float*)d_in[6];
    const float* be1 = (const float*)d_in[7];
    const float* w2a = (const float*)d_in[8];
    const float* b2a = (const float*)d_in[9];
    const float* w2b = (const float*)d_in[10];
    const float* b2b = (const float*)d_in[11];
    const float* g2  = (const float*)d_in[12];
    const float* be2 = (const float*)d_in[13];
    const float* wl  = (const float*)d_in[14];
    const float* bl  = (const float*)d_in[15];

    float* out = (float*)d_out;

    // workspace layout (halfs)
    const size_t WN   = (size_t)FF * DD * KK;          // 1,769,472 per weight comp
    const size_t SN   = (size_t)BB * PADL * DD;        // 6,303,744
    const size_t H1N  = (size_t)BB * PADL * FF;        // 25,214,976
    _Float16* p = (_Float16*)d_ws;
    _Float16* Wh1a = p;              _Float16* Wl1a = Wh1a + WN;
    _Float16* Wh1b = Wl1a + WN;      _Float16* Wl1b = Wh1b + WN;
    _Float16* Wh2a = Wl1b + WN;      _Float16* Wl2a = Wh2a + WN;
    _Float16* Wh2b = Wl2a + WN;      _Float16* Wl2b = Wh2b + WN;
    _Float16* Shi  = Wl2b + WN;      _Float16* Slo  = Shi + SN;
    _Float16* H1hi = Slo + SN;       _Float16* H1lo = H1hi + H1N;
    int* lns  = (int*)(H1lo + H1N);
    int* csum = lns + BB * LL;

    const int M = BB * LL;                              // 16384

    // 1) weight transpose+split, y split, pad-zero for H1
    {
        int n = FF * DD * KK;
        wsplit_k<<<(n + 255) / 256, 256, 0, stream>>>(w1a, Wh1a, Wl1a, FF, DD);
        wsplit_k<<<(n + 255) / 256, 256, 0, stream>>>(w1b, Wh1b, Wl1b, DD, FF);
        wsplit_k<<<(n + 255) / 256, 256, 0, stream>>>(w2a, Wh2a, Wl2a, FF, DD);
        wsplit_k<<<(n + 255) / 256, 256, 0, stream>>>(w2b, Wh2b, Wl2b, DD, FF);
        int ny = BB * PADL * DD;
        ysplit_k<<<(ny + 255) / 256, 256, 0, stream>>>(y, Shi, Slo);
        int np = BB * 2 * FF;
        padzero_k<<<(np + 255) / 256, 256, 0, stream>>>(H1hi, H1lo, FF);
    }
    // 2) four conv-GEMMs (S and H1 ping-pong; kernel order serializes reuse)
    gemm_split<<<dim3(FF / 128, M / 128), 256, 0, stream>>>(Shi, Slo, Wh1a, Wl1a, b1a, H1hi, H1lo, DD, FF, 3 * DD, DD / 32);
    gemm_split<<<dim3(DD / 128, M / 128), 256, 0, stream>>>(H1hi, H1lo, Wh1b, Wl1b, b1b, Shi, Slo, FF, DD, 3 * FF, FF / 32);
    ln_split_k<<<M, 128, 0, stream>>>(Shi, Slo, g1, be1);
    gemm_split<<<dim3(FF / 128, M / 128), 256, 0, stream>>>(Shi, Slo, Wh2a, Wl2a, b2a, H1hi, H1lo, DD, FF, 3 * DD, DD / 32);
    gemm_split<<<dim3(DD / 128, M / 128), 256, 0, stream>>>(H1hi, H1lo, Wh2b, Wl2b, b2b, Shi, Slo, FF, DD, 3 * FF, FF / 32);
    // 3) predictor + cumsum + gather
    ln_pred_split_k<<<M, 128, 0, stream>>>(Shi, Slo, g2, be2, wl, bl, tok, lns);
    cumsum_k<<<BB, 1024, 0, stream>>>(lns, csum, out + (size_t)BB * T_OUT * DD);
    {
        long long n = (long long)BB * T_OUT * 96;
        gather_k<<<(int)((n + 255) / 256), 256, 0, stream>>>(y, csum, out);
    }
}

// Round 3
// 1035.700 us; speedup vs baseline: 3.9291x; 1.1817x over previous
//
#include <hip/hip_runtime.h>
#include <hip/hip_bf16.h>

// Problem constants
#define BB 16
#define LL 1024
#define DD 384
#define FF 1536
#define KK 3
#define T_OUT 10240
#define MAX_DUR 10

#define PADL 1026                 // per-batch padded rows: [0]=zero, [1..1024]=data, [1025]=zero
#define LO_SCALE 2048.0f          // 2^11: keeps lo parts out of fp16-denormal range
#define LO_INV   4.8828125e-4f    // 2^-11

typedef _Float16 f16x8 __attribute__((ext_vector_type(8)));
typedef float    f32x4 __attribute__((ext_vector_type(4)));

__device__ __forceinline__ void gll16(const void* g, void* l) {
    __builtin_amdgcn_global_load_lds(
        (const __attribute__((address_space(1))) void*)g,
        (__attribute__((address_space(3))) void*)l, 16, 0, 0);
}

__device__ __forceinline__ void split_write(float v, _Float16* hi, _Float16* lo, size_t off) {
    _Float16 h = (_Float16)v;
    hi[off] = h;
    lo[off] = (_Float16)((v - (float)h) * LO_SCALE);
}

__device__ __forceinline__ float split_read(const _Float16* hi, const _Float16* lo, size_t off) {
    return (float)hi[off] + (float)lo[off] * LO_INV;
}

// ---------------- weight transpose+split: (O,I,3) -> [o][k*I+i] hi/lo -------
__global__ void wsplit_k(const float* __restrict__ w, _Float16* __restrict__ hi,
                         _Float16* __restrict__ lo, int O, int I) {
    int id = blockIdx.x * 256 + threadIdx.x;
    int n = O * I * 3;
    if (id >= n) return;
    int o = id / (3 * I);
    int rem = id - o * 3 * I;
    int k = rem / I;
    int i = rem - k * I;
    float v = w[(o * I + i) * 3 + k];
    split_write(v, hi, lo, id);
}

// ---------------- y split into padded hi/lo layout ---------------------------
__global__ void ysplit_k(const float* __restrict__ y, _Float16* __restrict__ hi,
                         _Float16* __restrict__ lo) {
    int id = blockIdx.x * 256 + threadIdx.x;     // BB*PADL*DD
    if (id >= BB * PADL * DD) return;
    int d = id % DD;
    int r = id / DD;
    int b = r / PADL;
    int lr = r - b * PADL;
    float v = 0.f;
    if (lr >= 1 && lr <= LL) v = y[((size_t)(b << 10) + (lr - 1)) * DD + d];
    split_write(v, hi, lo, id);
}

// ---------------- zero the halo pad rows of a padded split buffer ------------
__global__ void padzero_k(_Float16* __restrict__ hi, _Float16* __restrict__ lo, int width) {
    int id = blockIdx.x * 256 + threadIdx.x;     // BB*2*width
    if (id >= BB * 2 * width) return;
    int b = id / (2 * width);
    int rem = id - b * 2 * width;
    int row = (rem / width) ? (PADL - 1) : 0;
    int c = rem % width;
    size_t off = (size_t)(b * PADL + row) * width + c;
    hi[off] = (_Float16)0.f;
    lo[off] = (_Float16)0.f;
}

// ---------------- split-fp16 MFMA conv-GEMM, double-buffered -----------------
// C[m][n] = relu( sum_kk A[m][kk] * W2[n][kk] + bias[n] ),  kk = kseg*Cin + d
// K-loop: kseg fastest (kt%3) so A-row re-reads across the 3 taps are
// temporally adjacent -> L2 hits instead of HBM re-fetch.
// 1-D grid with XCD remap: m-tile %8 selects XCD so the nN n-peers of an
// m-tile co-reside on one XCD (A fetched from HBM once).
// LDS: two 32 KB buffers (Ahi|Alo|Bhi|Blo @ 8 KB each), prefetch k-tile t+1
// issued before the MFMA phase of tile t; single barrier per k-tile.
__global__ __launch_bounds__(256, 2) void gemm_split(
        const _Float16* __restrict__ Ahi, const _Float16* __restrict__ Alo,
        const _Float16* __restrict__ Whi, const _Float16* __restrict__ Wlo,
        const float* __restrict__ bias,
        _Float16* __restrict__ Ohi, _Float16* __restrict__ Olo,
        int Cin, int Cout, int Ktot, int nN) {
    __shared__ _Float16 lds_h[32768];   // 64 KB: 2 x (Ahi|Alo|Bhi|Blo)
    const int tid = threadIdx.x;
    const int lane = tid & 63;
    const int w = tid >> 6;
    const int lm = lane & 15, lq = lane >> 4;
    // XCD-aware remap of 1-D grid
    const int j = blockIdx.x;
    const int xcd = j & 7;
    const int t2 = j >> 3;
    const int n_t = t2 % nN;
    const int mt = (t2 / nN) * 8 + xcd;
    const int m0 = mt << 7;
    const int n0 = n_t << 7;
    const int b = m0 >> 10;
    const int l0 = m0 & 1023;
    const int rowBase = b * PADL + l0;           // + m + kseg = padded source row
    const int wm = (w >> 1) * 64, wn = (w & 1) * 64;

    f32x4 accM[4][4], accC[4][4];
    const f32x4 zz = {0.f, 0.f, 0.f, 0.f};
    #pragma unroll
    for (int i = 0; i < 4; ++i)
        #pragma unroll
        for (int jj = 0; jj < 4; ++jj) { accM[i][jj] = zz; accC[i][jj] = zz; }

    const int nKT = Ktot >> 5;

    // staging lambda: stage k-tile kt into buffer nxt
    auto stage = [&](int kt, int nxt) {
        int kseg = kt % 3;
        int d0 = (kt / 3) << 5;
        int kk0 = kseg * Cin + d0;
        #pragma unroll
        for (int it = 0; it < 2; ++it) {
            int s = (w * 2 + it) * 64 + lane;    // 16B-slot index 0..511
            int p = s >> 3, sl = s & 7;
            int t = sl ^ (p & 7);
            int m = p * 2 + (t >> 2);
            int k8 = t & 3;
            size_t aoff = (size_t)(rowBase + m + kseg) * Cin + d0 + k8 * 8;
            size_t boff = (size_t)(n0 + m) * Ktot + kk0 + k8 * 8;
            _Float16* lbase = lds_h + nxt * 16384 + (size_t)(w * 2 + it) * 512;
            gll16(Ahi + aoff, lbase);
            gll16(Alo + aoff, lbase + 4096);
            gll16(Whi + boff, lbase + 8192);
            gll16(Wlo + boff, lbase + 12288);
        }
    };

    stage(0, 0);
    for (int kt = 0; kt < nKT; ++kt) {
        const int cur = kt & 1;
        __syncthreads();                          // buf[cur] staged; prior reads of buf[cur^1] done
        if (kt + 1 < nKT) stage(kt + 1, cur ^ 1);
        const _Float16* lb = lds_h + cur * 16384;
        f16x8 aH[4], aL[4], bH[4], bL[4];
        #pragma unroll
        for (int i = 0; i < 4; ++i) {
            int m = wm + i * 16 + lm;
            int p = m >> 1;
            int sl = (((m & 1) << 2) | lq) ^ (p & 7);
            int off = p * 64 + sl * 8;
            aH[i] = *(const f16x8*)(lb + off);
            aL[i] = *(const f16x8*)(lb + 4096 + off);
            int n = wn + i * 16 + lm;
            int pn = n >> 1;
            int sln = (((n & 1) << 2) | lq) ^ (pn & 7);
            int offn = pn * 64 + sln * 8;
            bH[i] = *(const f16x8*)(lb + 8192 + offn);
            bL[i] = *(const f16x8*)(lb + 12288 + offn);
        }
        #pragma unroll
        for (int i = 0; i < 4; ++i)
            #pragma unroll
            for (int jj = 0; jj < 4; ++jj) {
                accM[i][jj] = __builtin_amdgcn_mfma_f32_16x16x32_f16(aH[i], bH[jj], accM[i][jj], 0, 0, 0);
                accC[i][jj] = __builtin_amdgcn_mfma_f32_16x16x32_f16(aH[i], bL[jj], accC[i][jj], 0, 0, 0);
                accC[i][jj] = __builtin_amdgcn_mfma_f32_16x16x32_f16(aL[i], bH[jj], accC[i][jj], 0, 0, 0);
            }
    }
    // epilogue: bias + relu + re-split to padded hi/lo output
    #pragma unroll
    for (int i = 0; i < 4; ++i)
        #pragma unroll
        for (int jj = 0; jj < 4; ++jj) {
            int n_g = n0 + wn + jj * 16 + lm;
            float bv = bias[n_g];
            #pragma unroll
            for (int r = 0; r < 4; ++r) {
                int l = l0 + wm + i * 16 + lq * 4 + r;
                float v = accM[i][jj][r] + accC[i][jj][r] * LO_INV + bv;
                v = fmaxf(v, 0.f);
                size_t off = (size_t)(b * PADL + 1 + l) * Cout + n_g;
                split_write(v, Ohi, Olo, off);
            }
        }
}

// ---------------- layernorm in place on split buffer (width 384) -------------
__global__ __launch_bounds__(128) void ln_split_k(
        _Float16* __restrict__ hi, _Float16* __restrict__ lo,
        const float* __restrict__ g, const float* __restrict__ be) {
    const int row = blockIdx.x;
    const int b = row >> 10, l = row & 1023;
    const size_t base = (size_t)(b * PADL + 1 + l) * DD;
    const int tid = threadIdx.x;
    float v0 = split_read(hi, lo, base + tid);
    float v1 = split_read(hi, lo, base + tid + 128);
    float v2 = split_read(hi, lo, base + tid + 256);

    __shared__ float sh[2];
    float s = v0 + v1 + v2;
    #pragma unroll
    for (int o = 32; o > 0; o >>= 1) s += __shfl_down(s, o, 64);
    if ((tid & 63) == 0) sh[tid >> 6] = s;
    __syncthreads();
    float mu = (sh[0] + sh[1]) * (1.f / DD);
    __syncthreads();
    float d0 = v0 - mu, d1 = v1 - mu, d2 = v2 - mu;
    float q = d0 * d0 + d1 * d1 + d2 * d2;
    #pragma unroll
    for (int o = 32; o > 0; o >>= 1) q += __shfl_down(q, o, 64);
    if ((tid & 63) == 0) sh[tid >> 6] = q;
    __syncthreads();
    float var = (sh[0] + sh[1]) * (1.f / DD);
    float rs = rsqrtf(var + 1e-5f);
    split_write(d0 * rs * g[tid] + be[tid], hi, lo, base + tid);
    split_write(d1 * rs * g[tid + 128] + be[tid + 128], hi, lo, base + tid + 128);
    split_write(d2 * rs * g[tid + 256] + be[tid + 256], hi, lo, base + tid + 256);
}

// ---------------- layernorm + length predictor on split buffer ---------------
__global__ __launch_bounds__(128) void ln_pred_split_k(
        const _Float16* __restrict__ hi, const _Float16* __restrict__ lo,
        const float* __restrict__ g, const float* __restrict__ be,
        const float* __restrict__ wl, const float* __restrict__ bl,
        const int* __restrict__ token_lengths, int* __restrict__ lns) {
    const int row = blockIdx.x;
    const int b = row >> 10, l = row & 1023;
    const size_t base = (size_t)(b * PADL + 1 + l) * DD;
    const int tid = threadIdx.x;
    float v0 = split_read(hi, lo, base + tid);
    float v1 = split_read(hi, lo, base + tid + 128);
    float v2 = split_read(hi, lo, base + tid + 256);

    __shared__ float sh[2];
    float s = v0 + v1 + v2;
    #pragma unroll
    for (int o = 32; o > 0; o >>= 1) s += __shfl_down(s, o, 64);
    if ((tid & 63) == 0) sh[tid >> 6] = s;
    __syncthreads();
    float mu = (sh[0] + sh[1]) * (1.f / DD);
    __syncthreads();
    float d0 = v0 - mu, d1 = v1 - mu, d2 = v2 - mu;
    float q = d0 * d0 + d1 * d1 + d2 * d2;
    #pragma unroll
    for (int o = 32; o > 0; o >>= 1) q += __shfl_down(q, o, 64);
    if ((tid & 63) == 0) sh[tid >> 6] = q;
    __syncthreads();
    float var = (sh[0] + sh[1]) * (1.f / DD);
    float rs = rsqrtf(var + 1e-5f);
    __syncthreads();
    float p = (d0 * rs * g[tid]       + be[tid])       * wl[tid]
            + (d1 * rs * g[tid + 128] + be[tid + 128]) * wl[tid + 128]
            + (d2 * rs * g[tid + 256] + be[tid + 256]) * wl[tid + 256];
    #pragma unroll
    for (int o = 32; o > 0; o >>= 1) p += __shfl_down(p, o, 64);
    if ((tid & 63) == 0) sh[tid >> 6] = p;
    __syncthreads();
    if (tid == 0) {
        float pred = sh[0] + sh[1] + bl[0];
        float e = expf(pred);           // ALPHA == 1.0
        float r = rintf(e);             // round-half-even, matches jnp.round
        r = fminf(fmaxf(r, 0.f), (float)MAX_DUR);
        int v = (int)r;
        if (l >= token_lengths[b]) v = 0;
        lns[row] = v;
    }
}

// ---------------- per-batch inclusive cumsum (L=1024) ------------------------
__global__ __launch_bounds__(1024) void cumsum_k(
        const int* __restrict__ lns, int* __restrict__ csum,
        float* __restrict__ totals_out) {
    __shared__ int s[1024];
    const int b = blockIdx.x, tid = threadIdx.x;
    s[tid] = lns[(b << 10) + tid];
    __syncthreads();
    #pragma unroll
    for (int o = 1; o < 1024; o <<= 1) {
        int t = (tid >= o) ? s[tid - o] : 0;
        __syncthreads();
        s[tid] += t;
        __syncthreads();
    }
    csum[(b << 10) + tid] = s[tid];
    if (tid == 1023) totals_out[b] = (float)s[1023];
}

// ---------------- gather: out[b,t,:] = valid ? y[b, idx(t), :] : 0 -----------
__global__ __launch_bounds__(256) void gather_k(
        const float* __restrict__ y, const int* __restrict__ csum,
        float* __restrict__ out) {
    int gid = blockIdx.x * 256 + threadIdx.x;   // B*T_OUT*96 float4 chunks
    int c4 = gid % 96;
    int rest = gid / 96;
    int t = rest % T_OUT;
    int b = rest / T_OUT;
    const int* c = csum + (b << 10);
    int total = c[1023];
    float4 r = make_float4(0.f, 0.f, 0.f, 0.f);
    if (t < total) {
        int lo = 0, hi = 1024;
        while (lo < hi) {               // searchsorted side='right'
            int mid = (lo + hi) >> 1;
            if (c[mid] <= t) lo = mid + 1; else hi = mid;
        }
        int idx = min(lo, LL - 1);
        r = *(const float4*)(y + ((size_t)((b << 10) + idx)) * DD + (c4 << 2));
    }
    *(float4*)(out + ((size_t)b * T_OUT + t) * DD + (c4 << 2)) = r;
}

// ---------------- host side --------------------------------------------------
extern "C" void kernel_launch(void* const* d_in, const int* in_sizes, int n_in,
                              void* d_out, int out_size, void* d_ws, size_t ws_size,
                              hipStream_t stream) {
    const float* y   = (const float*)d_in[0];
    const int*   tok = (const int*)d_in[1];
    const float* w1a = (const float*)d_in[2];
    const float* b1a = (const float*)d_in[3];
    const float* w1b = (const float*)d_in[4];
    const float* b1b = (const float*)d_in[5];
    const float* g1  = (const float*)d_in[6];
    const float* be1 = (const float*)d_in[7];
    const float* w2a = (const float*)d_in[8];
    const float* b2a = (const float*)d_in[9];
    const float* w2b = (const float*)d_in[10];
    const float* b2b = (const float*)d_in[11];
    const float* g2  = (const float*)d_in[12];
    const float* be2 = (const float*)d_in[13];
    const float* wl  = (const float*)d_in[14];
    const float* bl  = (const float*)d_in[15];

    float* out = (float*)d_out;

    // workspace layout (halfs)
    const size_t WN   = (size_t)FF * DD * KK;          // 1,769,472 per weight comp
    const size_t SN   = (size_t)BB * PADL * DD;        // 6,303,744
    const size_t H1N  = (size_t)BB * PADL * FF;        // 25,214,976
    _Float16* p = (_Float16*)d_ws;
    _Float16* Wh1a = p;              _Float16* Wl1a = Wh1a + WN;
    _Float16* Wh1b = Wl1a + WN;      _Float16* Wl1b = Wh1b + WN;
    _Float16* Wh2a = Wl1b + WN;      _Float16* Wl2a = Wh2a + WN;
    _Float16* Wh2b = Wl2a + WN;      _Float16* Wl2b = Wh2b + WN;
    _Float16* Shi  = Wl2b + WN;      _Float16* Slo  = Shi + SN;
    _Float16* H1hi = Slo + SN;       _Float16* H1lo = H1hi + H1N;
    int* lns  = (int*)(H1lo + H1N);
    int* csum = lns + BB * LL;

    const int M = BB * LL;                              // 16384

    // 1) weight transpose+split, y split, pad-zero for H1
    {
        int n = FF * DD * KK;
        wsplit_k<<<(n + 255) / 256, 256, 0, stream>>>(w1a, Wh1a, Wl1a, FF, DD);
        wsplit_k<<<(n + 255) / 256, 256, 0, stream>>>(w1b, Wh1b, Wl1b, DD, FF);
        wsplit_k<<<(n + 255) / 256, 256, 0, stream>>>(w2a, Wh2a, Wl2a, FF, DD);
        wsplit_k<<<(n + 255) / 256, 256, 0, stream>>>(w2b, Wh2b, Wl2b, DD, FF);
        int ny = BB * PADL * DD;
        ysplit_k<<<(ny + 255) / 256, 256, 0, stream>>>(y, Shi, Slo);
        int np = BB * 2 * FF;
        padzero_k<<<(np + 255) / 256, 256, 0, stream>>>(H1hi, H1lo, FF);
    }
    // 2) four conv-GEMMs (1-D grids, XCD-remapped in-kernel)
    gemm_split<<<(FF / 128) * (M / 128), 256, 0, stream>>>(Shi, Slo, Wh1a, Wl1a, b1a, H1hi, H1lo, DD, FF, 3 * DD, FF / 128);
    gemm_split<<<(DD / 128) * (M / 128), 256, 0, stream>>>(H1hi, H1lo, Wh1b, Wl1b, b1b, Shi, Slo, FF, DD, 3 * FF, DD / 128);
    ln_split_k<<<M, 128, 0, stream>>>(Shi, Slo, g1, be1);
    gemm_split<<<(FF / 128) * (M / 128), 256, 0, stream>>>(Shi, Slo, Wh2a, Wl2a, b2a, H1hi, H1lo, DD, FF, 3 * DD, FF / 128);
    gemm_split<<<(DD / 128) * (M / 128), 256, 0, stream>>>(H1hi, H1lo, Wh2b, Wl2b, b2b, Shi, Slo, FF, DD, 3 * FF, DD / 128);
    // 3) predictor + cumsum + gather
    ln_pred_split_k<<<M, 128, 0, stream>>>(Shi, Slo, g2, be2, wl, bl, tok, lns);
    cumsum_k<<<BB, 1024, 0, stream>>>(lns, csum, out + (size_t)BB * T_OUT * DD);
    {
        long long n = (long long)BB * T_OUT * 96;
        gather_k<<<(int)((n + 255) / 256), 256, 0, stream>>>(y, csum, out);
    }
}

// Round 4
// 1034.781 us; speedup vs baseline: 3.9326x; 1.0009x over previous
//
#include <hip/hip_runtime.h>
#include <hip/hip_bf16.h>

// Problem constants
#define BB 16
#define LL 1024
#define DD 384
#define FF 1536
#define KK 3
#define T_OUT 10240
#define MAX_DUR 10

#define PADL 1026                 // per-batch padded rows: [0]=zero, [1..1024]=data, [1025]=zero
#define LO_SCALE 2048.0f          // 2^11: keeps lo parts out of fp16-denormal range
#define LO_INV   4.8828125e-4f    // 2^-11

typedef _Float16 f16x8 __attribute__((ext_vector_type(8)));
typedef float    f32x4 __attribute__((ext_vector_type(4)));

__device__ __forceinline__ void gll16(const void* g, void* l) {
    __builtin_amdgcn_global_load_lds(
        (const __attribute__((address_space(1))) void*)g,
        (__attribute__((address_space(3))) void*)l, 16, 0, 0);
}

__device__ __forceinline__ void split_write(float v, _Float16* hi, _Float16* lo, size_t off) {
    _Float16 h = (_Float16)v;
    hi[off] = h;
    lo[off] = (_Float16)((v - (float)h) * LO_SCALE);
}

__device__ __forceinline__ float split_read(const _Float16* hi, const _Float16* lo, size_t off) {
    return (float)hi[off] + (float)lo[off] * LO_INV;
}

// ---- weight pack: (O,I,3) -> MFMA-fragment-major hi/lo --------------------
// frag layout: [o_tile][ktl][lane][e8], 8 halfs per lane (16 B), so a wave's
// b-frag load is base + lane*16 (one coalesced global_load_dwordx4).
// ktl ordering matches the GEMM k-loop: kseg = ktl%3 (fastest), d0 = (ktl/3)*32.
// lane: n_local = lane&15, k-quad = lane>>4; elem e: koff = kq*8 + e.
__global__ void wfrag_k(const float* __restrict__ w, _Float16* __restrict__ hi,
                        _Float16* __restrict__ lo, int O, int I) {
    int id = blockIdx.x * 256 + threadIdx.x;
    int total = O * 3 * I;
    if (id >= total) return;
    int e = id & 7;
    int lane = (id >> 3) & 63;
    int rest = id >> 9;              // o_tile * nKT + ktl
    int nKT = (3 * I) >> 5;
    int ktl = rest % nKT;
    int ot = rest / nKT;
    int o = ot * 16 + (lane & 15);
    int koff = ((lane >> 4) << 3) + e;
    int kseg = ktl % 3;
    int i = (ktl / 3) * 32 + koff;
    float v = w[(o * I + i) * 3 + kseg];
    split_write(v, hi, lo, id);
}

// ---------------- y split into padded hi/lo layout ---------------------------
__global__ void ysplit_k(const float* __restrict__ y, _Float16* __restrict__ hi,
                         _Float16* __restrict__ lo) {
    int id = blockIdx.x * 256 + threadIdx.x;     // BB*PADL*DD
    if (id >= BB * PADL * DD) return;
    int d = id % DD;
    int r = id / DD;
    int b = r / PADL;
    int lr = r - b * PADL;
    float v = 0.f;
    if (lr >= 1 && lr <= LL) v = y[((size_t)(b << 10) + (lr - 1)) * DD + d];
    split_write(v, hi, lo, id);
}

// ---------------- zero the halo pad rows of a padded split buffer ------------
__global__ void padzero_k(_Float16* __restrict__ hi, _Float16* __restrict__ lo, int width) {
    int id = blockIdx.x * 256 + threadIdx.x;     // BB*2*width
    if (id >= BB * 2 * width) return;
    int b = id / (2 * width);
    int rem = id - b * 2 * width;
    int row = (rem / width) ? (PADL - 1) : 0;
    int c = rem % width;
    size_t off = (size_t)(b * PADL + row) * width + c;
    hi[off] = (_Float16)0.f;
    lo[off] = (_Float16)0.f;
}

// ---------------- split-fp16 MFMA conv-GEMM ----------------------------------
// A (activations) via LDS double-buffer (16 KB/buf: Ahi|Alo), staged with
// global_load_lds width-16. B (weights) read per-k-tile directly to registers
// from the fragment-major pack (L1/L2-served, coalesced 16 B/lane).
// Grid swizzle: xcd = blk&7; per XCD, groups of 4 m-tiles sweep all n-tiles
// (B panel and A group both L2-hot).
__global__ __launch_bounds__(256, 2) void gemm_split(
        const _Float16* __restrict__ Ahi, const _Float16* __restrict__ Alo,
        const _Float16* __restrict__ WfH, const _Float16* __restrict__ WfL,
        const float* __restrict__ bias,
        _Float16* __restrict__ Ohi, _Float16* __restrict__ Olo,
        int Cin, int Cout, int Ktot, int nN) {
    __shared__ _Float16 lds_h[16384];   // 32 KB: 2 x (Ahi 8KB | Alo 8KB)
    const int tid = threadIdx.x;
    const int lane = tid & 63;
    const int w = tid >> 6;
    const int lm = lane & 15, lq = lane >> 4;
    // XCD-aware remap: group-of-4 m-tiles, n fastest inside the group
    const int xcd = blockIdx.x & 7;
    const int t2 = blockIdx.x >> 3;
    const int g  = t2 / (4 * nN);
    const int r  = t2 - g * (4 * nN);
    const int n_t = r >> 2;
    const int mi  = r & 3;
    const int m_t = ((g * 4 + mi) << 3) + xcd;
    const int m0 = m_t << 7;
    const int n0 = n_t << 7;
    const int b = m0 >> 10;
    const int l0 = m0 & 1023;
    const int rowBase = b * PADL + l0;           // + m + kseg = padded source row
    const int wm = (w >> 1) * 64, wn = (w & 1) * 64;

    f32x4 accM[4][4], accC[4][4];
    const f32x4 zz = {0.f, 0.f, 0.f, 0.f};
    #pragma unroll
    for (int i = 0; i < 4; ++i)
        #pragma unroll
        for (int jj = 0; jj < 4; ++jj) { accM[i][jj] = zz; accC[i][jj] = zz; }

    const int nKT = Ktot >> 5;

    // stage A k-tile kt into LDS buffer nxt (512 slots x 16 B per comp)
    auto stageA = [&](int kt, int nxt) {
        int kseg = kt % 3;
        int d0 = (kt / 3) << 5;
        #pragma unroll
        for (int it = 0; it < 2; ++it) {
            int s = (w * 2 + it) * 64 + lane;    // 16B-slot index 0..511
            int p = s >> 3, sl = s & 7;
            int t = sl ^ (p & 7);
            int m = p * 2 + (t >> 2);
            int k8 = t & 3;
            size_t aoff = (size_t)(rowBase + m + kseg) * Cin + d0 + k8 * 8;
            _Float16* lbase = lds_h + nxt * 8192 + (size_t)(w * 2 + it) * 512;
            gll16(Ahi + aoff, lbase);
            gll16(Alo + aoff, lbase + 4096);
        }
    };

    stageA(0, 0);
    for (int kt = 0; kt < nKT; ++kt) {
        const int cur = kt & 1;
        __syncthreads();                          // buf[cur] staged; prior reads of buf[cur^1] done
        // B fragments for this k-tile: direct global->register, coalesced
        f16x8 bH[4], bL[4];
        #pragma unroll
        for (int jj = 0; jj < 4; ++jj) {
            int ntg = (n0 + wn + jj * 16) >> 4;
            size_t boff = (((size_t)ntg * nKT + kt) * 64 + lane) * 8;
            bH[jj] = *(const f16x8*)(WfH + boff);
            bL[jj] = *(const f16x8*)(WfL + boff);
        }
        if (kt + 1 < nKT) stageA(kt + 1, cur ^ 1);
        const _Float16* lb = lds_h + cur * 8192;
        f16x8 aH[4], aL[4];
        #pragma unroll
        for (int i = 0; i < 4; ++i) {
            int m = wm + i * 16 + lm;
            int p = m >> 1;
            int sl = (((m & 1) << 2) | lq) ^ (p & 7);
            int off = p * 64 + sl * 8;
            aH[i] = *(const f16x8*)(lb + off);
            aL[i] = *(const f16x8*)(lb + 4096 + off);
        }
        #pragma unroll
        for (int jj = 0; jj < 4; ++jj)            // j-outer: consume earliest load first
            #pragma unroll
            for (int i = 0; i < 4; ++i) {
                accM[i][jj] = __builtin_amdgcn_mfma_f32_16x16x32_f16(aH[i], bH[jj], accM[i][jj], 0, 0, 0);
                accC[i][jj] = __builtin_amdgcn_mfma_f32_16x16x32_f16(aH[i], bL[jj], accC[i][jj], 0, 0, 0);
                accC[i][jj] = __builtin_amdgcn_mfma_f32_16x16x32_f16(aL[i], bH[jj], accC[i][jj], 0, 0, 0);
            }
    }
    // epilogue: bias + relu + re-split to padded hi/lo output
    #pragma unroll
    for (int i = 0; i < 4; ++i)
        #pragma unroll
        for (int jj = 0; jj < 4; ++jj) {
            int n_g = n0 + wn + jj * 16 + lm;
            float bv = bias[n_g];
            #pragma unroll
            for (int rr = 0; rr < 4; ++rr) {
                int l = l0 + wm + i * 16 + lq * 4 + rr;
                float v = accM[i][jj][rr] + accC[i][jj][rr] * LO_INV + bv;
                v = fmaxf(v, 0.f);
                size_t off = (size_t)(b * PADL + 1 + l) * Cout + n_g;
                split_write(v, Ohi, Olo, off);
            }
        }
}

// ---------------- layernorm in place on split buffer (width 384) -------------
__global__ __launch_bounds__(128) void ln_split_k(
        _Float16* __restrict__ hi, _Float16* __restrict__ lo,
        const float* __restrict__ g, const float* __restrict__ be) {
    const int row = blockIdx.x;
    const int b = row >> 10, l = row & 1023;
    const size_t base = (size_t)(b * PADL + 1 + l) * DD;
    const int tid = threadIdx.x;
    float v0 = split_read(hi, lo, base + tid);
    float v1 = split_read(hi, lo, base + tid + 128);
    float v2 = split_read(hi, lo, base + tid + 256);

    __shared__ float sh[2];
    float s = v0 + v1 + v2;
    #pragma unroll
    for (int o = 32; o > 0; o >>= 1) s += __shfl_down(s, o, 64);
    if ((tid & 63) == 0) sh[tid >> 6] = s;
    __syncthreads();
    float mu = (sh[0] + sh[1]) * (1.f / DD);
    __syncthreads();
    float d0 = v0 - mu, d1 = v1 - mu, d2 = v2 - mu;
    float q = d0 * d0 + d1 * d1 + d2 * d2;
    #pragma unroll
    for (int o = 32; o > 0; o >>= 1) q += __shfl_down(q, o, 64);
    if ((tid & 63) == 0) sh[tid >> 6] = q;
    __syncthreads();
    float var = (sh[0] + sh[1]) * (1.f / DD);
    float rs = rsqrtf(var + 1e-5f);
    split_write(d0 * rs * g[tid] + be[tid], hi, lo, base + tid);
    split_write(d1 * rs * g[tid + 128] + be[tid + 128], hi, lo, base + tid + 128);
    split_write(d2 * rs * g[tid + 256] + be[tid + 256], hi, lo, base + tid + 256);
}

// ---------------- layernorm + length predictor on split buffer ---------------
__global__ __launch_bounds__(128) void ln_pred_split_k(
        const _Float16* __restrict__ hi, const _Float16* __restrict__ lo,
        const float* __restrict__ g, const float* __restrict__ be,
        const float* __restrict__ wl, const float* __restrict__ bl,
        const int* __restrict__ token_lengths, int* __restrict__ lns) {
    const int row = blockIdx.x;
    const int b = row >> 10, l = row & 1023;
    const size_t base = (size_t)(b * PADL + 1 + l) * DD;
    const int tid = threadIdx.x;
    float v0 = split_read(hi, lo, base + tid);
    float v1 = split_read(hi, lo, base + tid + 128);
    float v2 = split_read(hi, lo, base + tid + 256);

    __shared__ float sh[2];
    float s = v0 + v1 + v2;
    #pragma unroll
    for (int o = 32; o > 0; o >>= 1) s += __shfl_down(s, o, 64);
    if ((tid & 63) == 0) sh[tid >> 6] = s;
    __syncthreads();
    float mu = (sh[0] + sh[1]) * (1.f / DD);
    __syncthreads();
    float d0 = v0 - mu, d1 = v1 - mu, d2 = v2 - mu;
    float q = d0 * d0 + d1 * d1 + d2 * d2;
    #pragma unroll
    for (int o = 32; o > 0; o >>= 1) q += __shfl_down(q, o, 64);
    if ((tid & 63) == 0) sh[tid >> 6] = q;
    __syncthreads();
    float var = (sh[0] + sh[1]) * (1.f / DD);
    float rs = rsqrtf(var + 1e-5f);
    __syncthreads();
    float p = (d0 * rs * g[tid]       + be[tid])       * wl[tid]
            + (d1 * rs * g[tid + 128] + be[tid + 128]) * wl[tid + 128]
            + (d2 * rs * g[tid + 256] + be[tid + 256]) * wl[tid + 256];
    #pragma unroll
    for (int o = 32; o > 0; o >>= 1) p += __shfl_down(p, o, 64);
    if ((tid & 63) == 0) sh[tid >> 6] = p;
    __syncthreads();
    if (tid == 0) {
        float pred = sh[0] + sh[1] + bl[0];
        float e = expf(pred);           // ALPHA == 1.0
        float r = rintf(e);             // round-half-even, matches jnp.round
        r = fminf(fmaxf(r, 0.f), (float)MAX_DUR);
        int v = (int)r;
        if (l >= token_lengths[b]) v = 0;
        lns[row] = v;
    }
}

// ---------------- per-batch inclusive cumsum (L=1024) ------------------------
__global__ __launch_bounds__(1024) void cumsum_k(
        const int* __restrict__ lns, int* __restrict__ csum,
        float* __restrict__ totals_out) {
    __shared__ int s[1024];
    const int b = blockIdx.x, tid = threadIdx.x;
    s[tid] = lns[(b << 10) + tid];
    __syncthreads();
    #pragma unroll
    for (int o = 1; o < 1024; o <<= 1) {
        int t = (tid >= o) ? s[tid - o] : 0;
        __syncthreads();
        s[tid] += t;
        __syncthreads();
    }
    csum[(b << 10) + tid] = s[tid];
    if (tid == 1023) totals_out[b] = (float)s[1023];
}

// ---------------- gather: out[b,t,:] = valid ? y[b, idx(t), :] : 0 -----------
__global__ __launch_bounds__(256) void gather_k(
        const float* __restrict__ y, const int* __restrict__ csum,
        float* __restrict__ out) {
    int gid = blockIdx.x * 256 + threadIdx.x;   // B*T_OUT*96 float4 chunks
    int c4 = gid % 96;
    int rest = gid / 96;
    int t = rest % T_OUT;
    int b = rest / T_OUT;
    const int* c = csum + (b << 10);
    int total = c[1023];
    float4 r = make_float4(0.f, 0.f, 0.f, 0.f);
    if (t < total) {
        int lo = 0, hi = 1024;
        while (lo < hi) {               // searchsorted side='right'
            int mid = (lo + hi) >> 1;
            if (c[mid] <= t) lo = mid + 1; else hi = mid;
        }
        int idx = min(lo, LL - 1);
        r = *(const float4*)(y + ((size_t)((b << 10) + idx)) * DD + (c4 << 2));
    }
    *(float4*)(out + ((size_t)b * T_OUT + t) * DD + (c4 << 2)) = r;
}

// ---------------- host side --------------------------------------------------
extern "C" void kernel_launch(void* const* d_in, const int* in_sizes, int n_in,
                              void* d_out, int out_size, void* d_ws, size_t ws_size,
                              hipStream_t stream) {
    const float* y   = (const float*)d_in[0];
    const int*   tok = (const int*)d_in[1];
    const float* w1a = (const float*)d_in[2];
    const float* b1a = (const float*)d_in[3];
    const float* w1b = (const float*)d_in[4];
    const float* b1b = (const float*)d_in[5];
    const float* g1  = (const float*)d_in[6];
    const float* be1 = (const float*)d_in[7];
    const float* w2a = (const float*)d_in[8];
    const float* b2a = (const float*)d_in[9];
    const float* w2b = (const float*)d_in[10];
    const float* b2b = (const float*)d_in[11];
    const float* g2  = (const float*)d_in[12];
    const float* be2 = (const float*)d_in[13];
    const float* wl  = (const float*)d_in[14];
    const float* bl  = (const float*)d_in[15];

    float* out = (float*)d_out;

    // workspace layout (halfs)
    const size_t WN   = (size_t)FF * DD * KK;          // 1,769,472 per weight comp
    const size_t SN   = (size_t)BB * PADL * DD;        // 6,303,744
    const size_t H1N  = (size_t)BB * PADL * FF;        // 25,214,976
    _Float16* p = (_Float16*)d_ws;
    _Float16* Wh1a = p;              _Float16* Wl1a = Wh1a + WN;
    _Float16* Wh1b = Wl1a + WN;      _Float16* Wl1b = Wh1b + WN;
    _Float16* Wh2a = Wl1b + WN;      _Float16* Wl2a = Wh2a + WN;
    _Float16* Wh2b = Wl2a + WN;      _Float16* Wl2b = Wh2b + WN;
    _Float16* Shi  = Wl2b + WN;      _Float16* Slo  = Shi + SN;
    _Float16* H1hi = Slo + SN;       _Float16* H1lo = H1hi + H1N;
    int* lns  = (int*)(H1lo + H1N);
    int* csum = lns + BB * LL;

    const int M = BB * LL;                              // 16384

    // 1) weight frag-pack+split, y split, pad-zero for H1
    {
        int n = FF * DD * KK;
        wfrag_k<<<(n + 255) / 256, 256, 0, stream>>>(w1a, Wh1a, Wl1a, FF, DD);
        wfrag_k<<<(n + 255) / 256, 256, 0, stream>>>(w1b, Wh1b, Wl1b, DD, FF);
        wfrag_k<<<(n + 255) / 256, 256, 0, stream>>>(w2a, Wh2a, Wl2a, FF, DD);
        wfrag_k<<<(n + 255) / 256, 256, 0, stream>>>(w2b, Wh2b, Wl2b, DD, FF);
        int ny = BB * PADL * DD;
        ysplit_k<<<(ny + 255) / 256, 256, 0, stream>>>(y, Shi, Slo);
        int np = BB * 2 * FF;
        padzero_k<<<(np + 255) / 256, 256, 0, stream>>>(H1hi, H1lo, FF);
    }
    // 2) four conv-GEMMs (1-D grids, XCD-remapped in-kernel)
    gemm_split<<<(FF / 128) * (M / 128), 256, 0, stream>>>(Shi, Slo, Wh1a, Wl1a, b1a, H1hi, H1lo, DD, FF, 3 * DD, FF / 128);
    gemm_split<<<(DD / 128) * (M / 128), 256, 0, stream>>>(H1hi, H1lo, Wh1b, Wl1b, b1b, Shi, Slo, FF, DD, 3 * FF, DD / 128);
    ln_split_k<<<M, 128, 0, stream>>>(Shi, Slo, g1, be1);
    gemm_split<<<(FF / 128) * (M / 128), 256, 0, stream>>>(Shi, Slo, Wh2a, Wl2a, b2a, H1hi, H1lo, DD, FF, 3 * DD, FF / 128);
    gemm_split<<<(DD / 128) * (M / 128), 256, 0, stream>>>(H1hi, H1lo, Wh2b, Wl2b, b2b, Shi, Slo, FF, DD, 3 * FF, DD / 128);
    // 3) predictor + cumsum + gather
    ln_pred_split_k<<<M, 128, 0, stream>>>(Shi, Slo, g2, be2, wl, bl, tok, lns);
    cumsum_k<<<BB, 1024, 0, stream>>>(lns, csum, out + (size_t)BB * T_OUT * DD);
    {
        long long n = (long long)BB * T_OUT * 96;
        gather_k<<<(int)((n + 255) / 256), 256, 0, stream>>>(y, csum, out);
    }
}

// Round 5
// 1030.097 us; speedup vs baseline: 3.9505x; 1.0045x over previous
//
#include <hip/hip_runtime.h>
#include <hip/hip_bf16.h>

// Problem constants
#define BB 16
#define LL 1024
#define DD 384
#define FF 1536
#define KK 3
#define T_OUT 10240
#define MAX_DUR 10

#define PADL 1026                 // per-batch padded rows: [0]=zero, [1..1024]=data, [1025]=zero
#define LO_SCALE 2048.0f          // 2^11: keeps lo parts out of fp16-denormal range
#define LO_INV   4.8828125e-4f    // 2^-11

typedef _Float16 f16x8 __attribute__((ext_vector_type(8)));
typedef float    f32x4 __attribute__((ext_vector_type(4)));

__device__ __forceinline__ void gll16(const void* g, void* l) {
    __builtin_amdgcn_global_load_lds(
        (const __attribute__((address_space(1))) void*)g,
        (__attribute__((address_space(3))) void*)l, 16, 0, 0);
}

__device__ __forceinline__ void split_write(float v, _Float16* hi, _Float16* lo, size_t off) {
    _Float16 h = (_Float16)v;
    hi[off] = h;
    lo[off] = (_Float16)((v - (float)h) * LO_SCALE);
}

__device__ __forceinline__ float split_read(const _Float16* hi, const _Float16* lo, size_t off) {
    return (float)hi[off] + (float)lo[off] * LO_INV;
}

// ---- weight pack: (O,I,3) -> MFMA-fragment-major hi/lo --------------------
// frag layout: [o_tile][ktl][lane][e8], 8 halfs per lane (16 B), so a wave's
// b-frag load is base + lane*16 (one coalesced global_load_dwordx4).
// ktl ordering matches the GEMM k-loop: kseg = ktl%3 (fastest), d0 = (ktl/3)*32.
// lane: n_local = lane&15, k-quad = lane>>4; elem e: koff = kq*8 + e.
__global__ void wfrag_k(const float* __restrict__ w, _Float16* __restrict__ hi,
                        _Float16* __restrict__ lo, int O, int I) {
    int id = blockIdx.x * 256 + threadIdx.x;
    int total = O * 3 * I;
    if (id >= total) return;
    int e = id & 7;
    int lane = (id >> 3) & 63;
    int rest = id >> 9;              // o_tile * nKT + ktl
    int nKT = (3 * I) >> 5;
    int ktl = rest % nKT;
    int ot = rest / nKT;
    int o = ot * 16 + (lane & 15);
    int koff = ((lane >> 4) << 3) + e;
    int kseg = ktl % 3;
    int i = (ktl / 3) * 32 + koff;
    float v = w[(o * I + i) * 3 + kseg];
    split_write(v, hi, lo, id);
}

// ---------------- y split into padded hi/lo layout ---------------------------
__global__ void ysplit_k(const float* __restrict__ y, _Float16* __restrict__ hi,
                         _Float16* __restrict__ lo) {
    int id = blockIdx.x * 256 + threadIdx.x;     // BB*PADL*DD
    if (id >= BB * PADL * DD) return;
    int d = id % DD;
    int r = id / DD;
    int b = r / PADL;
    int lr = r - b * PADL;
    float v = 0.f;
    if (lr >= 1 && lr <= LL) v = y[((size_t)(b << 10) + (lr - 1)) * DD + d];
    split_write(v, hi, lo, id);
}

// ---------------- zero the halo pad rows of a padded split buffer ------------
__global__ void padzero_k(_Float16* __restrict__ hi, _Float16* __restrict__ lo, int width) {
    int id = blockIdx.x * 256 + threadIdx.x;     // BB*2*width
    if (id >= BB * 2 * width) return;
    int b = id / (2 * width);
    int rem = id - b * 2 * width;
    int row = (rem / width) ? (PADL - 1) : 0;
    int c = rem % width;
    size_t off = (size_t)(b * PADL + row) * width + c;
    hi[off] = (_Float16)0.f;
    lo[off] = (_Float16)0.f;
}

// ---------------- split-fp16 MFMA conv-GEMM ----------------------------------
// A (activations) via LDS double-buffer (16 KB/buf: Ahi|Alo), staged with
// global_load_lds width-16. B (weights) register-double-buffered: B(kt+1)
// global->reg loads issue right after the barrier, a full MFMA phase before
// use (hides vmem latency). K-loop unrolled x2 (two B reg sets, no copies).
__global__ __launch_bounds__(256, 2) void gemm_split(
        const _Float16* __restrict__ Ahi, const _Float16* __restrict__ Alo,
        const _Float16* __restrict__ WfH, const _Float16* __restrict__ WfL,
        const float* __restrict__ bias,
        _Float16* __restrict__ Ohi, _Float16* __restrict__ Olo,
        int Cin, int Cout, int Ktot, int nN) {
    __shared__ _Float16 lds_h[16384];   // 32 KB: 2 x (Ahi 8KB | Alo 8KB)
    const int tid = threadIdx.x;
    const int lane = tid & 63;
    const int w = tid >> 6;
    const int lm = lane & 15, lq = lane >> 4;
    // XCD-aware remap: group-of-4 m-tiles, n fastest inside the group
    const int xcd = blockIdx.x & 7;
    const int t2 = blockIdx.x >> 3;
    const int g  = t2 / (4 * nN);
    const int r  = t2 - g * (4 * nN);
    const int n_t = r >> 2;
    const int mi  = r & 3;
    const int m_t = ((g * 4 + mi) << 3) + xcd;
    const int m0 = m_t << 7;
    const int n0 = n_t << 7;
    const int b = m0 >> 10;
    const int l0 = m0 & 1023;
    const int rowBase = b * PADL + l0;           // + m + kseg = padded source row
    const int wm = (w >> 1) * 64, wn = (w & 1) * 64;

    f32x4 accM[4][4], accC[4][4];
    const f32x4 zz = {0.f, 0.f, 0.f, 0.f};
    #pragma unroll
    for (int i = 0; i < 4; ++i)
        #pragma unroll
        for (int jj = 0; jj < 4; ++jj) { accM[i][jj] = zz; accC[i][jj] = zz; }

    const int nKT = Ktot >> 5;

    // stage A k-tile kt into LDS buffer nxt (512 slots x 16 B per comp)
    auto stageA = [&](int kt, int nxt) {
        int kseg = kt % 3;
        int d0 = (kt / 3) << 5;
        #pragma unroll
        for (int it = 0; it < 2; ++it) {
            int s = (w * 2 + it) * 64 + lane;    // 16B-slot index 0..511
            int p = s >> 3, sl = s & 7;
            int t = sl ^ (p & 7);
            int m = p * 2 + (t >> 2);
            int k8 = t & 3;
            size_t aoff = (size_t)(rowBase + m + kseg) * Cin + d0 + k8 * 8;
            _Float16* lbase = lds_h + nxt * 8192 + (size_t)(w * 2 + it) * 512;
            gll16(Ahi + aoff, lbase);
            gll16(Alo + aoff, lbase + 4096);
        }
    };

    // B fragment load for k-tile kt (clamped; always in-bounds)
    auto loadB = [&](int kt, f16x8* bH, f16x8* bL) {
        int ktc = kt < nKT ? kt : nKT - 1;
        #pragma unroll
        for (int jj = 0; jj < 4; ++jj) {
            int ntg = (n0 + wn + jj * 16) >> 4;
            size_t boff = (((size_t)ntg * nKT + ktc) * 64 + lane) * 8;
            bH[jj] = *(const f16x8*)(WfH + boff);
            bL[jj] = *(const f16x8*)(WfL + boff);
        }
    };

    // MFMA phase for one staged k-tile (i-outer: one A frag pair live at a time)
    auto compute = [&](const _Float16* lb, const f16x8* bH, const f16x8* bL) {
        #pragma unroll
        for (int i = 0; i < 4; ++i) {
            int m = wm + i * 16 + lm;
            int p = m >> 1;
            int sl = (((m & 1) << 2) | lq) ^ (p & 7);
            int off = p * 64 + sl * 8;
            f16x8 aH = *(const f16x8*)(lb + off);
            f16x8 aL = *(const f16x8*)(lb + 4096 + off);
            #pragma unroll
            for (int jj = 0; jj < 4; ++jj) {
                accM[i][jj] = __builtin_amdgcn_mfma_f32_16x16x32_f16(aH, bH[jj], accM[i][jj], 0, 0, 0);
                accC[i][jj] = __builtin_amdgcn_mfma_f32_16x16x32_f16(aH, bL[jj], accC[i][jj], 0, 0, 0);
                accC[i][jj] = __builtin_amdgcn_mfma_f32_16x16x32_f16(aL, bH[jj], accC[i][jj], 0, 0, 0);
            }
        }
    };

    f16x8 b0H[4], b0L[4], b1H[4], b1L[4];
    loadB(0, b0H, b0L);
    stageA(0, 0);
    for (int kt = 0; kt < nKT; kt += 2) {
        __syncthreads();                      // A(kt) staged in buf0; b0 = B(kt)
        loadB(kt + 1, b1H, b1L);              // prefetch B(kt+1)
        if (kt + 1 < nKT) stageA(kt + 1, 1);  // prefetch A(kt+1)
        compute(lds_h, b0H, b0L);
        __syncthreads();                      // A(kt+1) staged in buf1; b1 = B(kt+1)
        loadB(kt + 2, b0H, b0L);              // prefetch B(kt+2)
        if (kt + 2 < nKT) stageA(kt + 2, 0);  // prefetch A(kt+2)
        if (kt + 1 < nKT) compute(lds_h + 8192, b1H, b1L);
    }
    // epilogue: bias + relu + re-split to padded hi/lo output
    #pragma unroll
    for (int i = 0; i < 4; ++i)
        #pragma unroll
        for (int jj = 0; jj < 4; ++jj) {
            int n_g = n0 + wn + jj * 16 + lm;
            float bv = bias[n_g];
            #pragma unroll
            for (int rr = 0; rr < 4; ++rr) {
                int l = l0 + wm + i * 16 + lq * 4 + rr;
                float v = accM[i][jj][rr] + accC[i][jj][rr] * LO_INV + bv;
                v = fmaxf(v, 0.f);
                size_t off = (size_t)(b * PADL + 1 + l) * Cout + n_g;
                split_write(v, Ohi, Olo, off);
            }
        }
}

// ---------------- layernorm in place on split buffer (width 384) -------------
__global__ __launch_bounds__(128) void ln_split_k(
        _Float16* __restrict__ hi, _Float16* __restrict__ lo,
        const float* __restrict__ g, const float* __restrict__ be) {
    const int row = blockIdx.x;
    const int b = row >> 10, l = row & 1023;
    const size_t base = (size_t)(b * PADL + 1 + l) * DD;
    const int tid = threadIdx.x;
    float v0 = split_read(hi, lo, base + tid);
    float v1 = split_read(hi, lo, base + tid + 128);
    float v2 = split_read(hi, lo, base + tid + 256);

    __shared__ float sh[2];
    float s = v0 + v1 + v2;
    #pragma unroll
    for (int o = 32; o > 0; o >>= 1) s += __shfl_down(s, o, 64);
    if ((tid & 63) == 0) sh[tid >> 6] = s;
    __syncthreads();
    float mu = (sh[0] + sh[1]) * (1.f / DD);
    __syncthreads();
    float d0 = v0 - mu, d1 = v1 - mu, d2 = v2 - mu;
    float q = d0 * d0 + d1 * d1 + d2 * d2;
    #pragma unroll
    for (int o = 32; o > 0; o >>= 1) q += __shfl_down(q, o, 64);
    if ((tid & 63) == 0) sh[tid >> 6] = q;
    __syncthreads();
    float var = (sh[0] + sh[1]) * (1.f / DD);
    float rs = rsqrtf(var + 1e-5f);
    split_write(d0 * rs * g[tid] + be[tid], hi, lo, base + tid);
    split_write(d1 * rs * g[tid + 128] + be[tid + 128], hi, lo, base + tid + 128);
    split_write(d2 * rs * g[tid + 256] + be[tid + 256], hi, lo, base + tid + 256);
}

// ---------------- layernorm + length predictor on split buffer ---------------
__global__ __launch_bounds__(128) void ln_pred_split_k(
        const _Float16* __restrict__ hi, const _Float16* __restrict__ lo,
        const float* __restrict__ g, const float* __restrict__ be,
        const float* __restrict__ wl, const float* __restrict__ bl,
        const int* __restrict__ token_lengths, int* __restrict__ lns) {
    const int row = blockIdx.x;
    const int b = row >> 10, l = row & 1023;
    const size_t base = (size_t)(b * PADL + 1 + l) * DD;
    const int tid = threadIdx.x;
    float v0 = split_read(hi, lo, base + tid);
    float v1 = split_read(hi, lo, base + tid + 128);
    float v2 = split_read(hi, lo, base + tid + 256);

    __shared__ float sh[2];
    float s = v0 + v1 + v2;
    #pragma unroll
    for (int o = 32; o > 0; o >>= 1) s += __shfl_down(s, o, 64);
    if ((tid & 63) == 0) sh[tid >> 6] = s;
    __syncthreads();
    float mu = (sh[0] + sh[1]) * (1.f / DD);
    __syncthreads();
    float d0 = v0 - mu, d1 = v1 - mu, d2 = v2 - mu;
    float q = d0 * d0 + d1 * d1 + d2 * d2;
    #pragma unroll
    for (int o = 32; o > 0; o >>= 1) q += __shfl_down(q, o, 64);
    if ((tid & 63) == 0) sh[tid >> 6] = q;
    __syncthreads();
    float var = (sh[0] + sh[1]) * (1.f / DD);
    float rs = rsqrtf(var + 1e-5f);
    __syncthreads();
    float p = (d0 * rs * g[tid]       + be[tid])       * wl[tid]
            + (d1 * rs * g[tid + 128] + be[tid + 128]) * wl[tid + 128]
            + (d2 * rs * g[tid + 256] + be[tid + 256]) * wl[tid + 256];
    #pragma unroll
    for (int o = 32; o > 0; o >>= 1) p += __shfl_down(p, o, 64);
    if ((tid & 63) == 0) sh[tid >> 6] = p;
    __syncthreads();
    if (tid == 0) {
        float pred = sh[0] + sh[1] + bl[0];
        float e = expf(pred);           // ALPHA == 1.0
        float r = rintf(e);             // round-half-even, matches jnp.round
        r = fminf(fmaxf(r, 0.f), (float)MAX_DUR);
        int v = (int)r;
        if (l >= token_lengths[b]) v = 0;
        lns[row] = v;
    }
}

// ---------------- per-batch inclusive cumsum (L=1024) ------------------------
__global__ __launch_bounds__(1024) void cumsum_k(
        const int* __restrict__ lns, int* __restrict__ csum,
        float* __restrict__ totals_out) {
    __shared__ int s[1024];
    const int b = blockIdx.x, tid = threadIdx.x;
    s[tid] = lns[(b << 10) + tid];
    __syncthreads();
    #pragma unroll
    for (int o = 1; o < 1024; o <<= 1) {
        int t = (tid >= o) ? s[tid - o] : 0;
        __syncthreads();
        s[tid] += t;
        __syncthreads();
    }
    csum[(b << 10) + tid] = s[tid];
    if (tid == 1023) totals_out[b] = (float)s[1023];
}

// ---------------- gather: out[b,t,:] = valid ? y[b, idx(t), :] : 0 -----------
__global__ __launch_bounds__(256) void gather_k(
        const float* __restrict__ y, const int* __restrict__ csum,
        float* __restrict__ out) {
    int gid = blockIdx.x * 256 + threadIdx.x;   // B*T_OUT*96 float4 chunks
    int c4 = gid % 96;
    int rest = gid / 96;
    int t = rest % T_OUT;
    int b = rest / T_OUT;
    const int* c = csum + (b << 10);
    int total = c[1023];
    float4 r = make_float4(0.f, 0.f, 0.f, 0.f);
    if (t < total) {
        int lo = 0, hi = 1024;
        while (lo < hi) {               // searchsorted side='right'
            int mid = (lo + hi) >> 1;
            if (c[mid] <= t) lo = mid + 1; else hi = mid;
        }
        int idx = min(lo, LL - 1);
        r = *(const float4*)(y + ((size_t)((b << 10) + idx)) * DD + (c4 << 2));
    }
    *(float4*)(out + ((size_t)b * T_OUT + t) * DD + (c4 << 2)) = r;
}

// ---------------- host side --------------------------------------------------
extern "C" void kernel_launch(void* const* d_in, const int* in_sizes, int n_in,
                              void* d_out, int out_size, void* d_ws, size_t ws_size,
                              hipStream_t stream) {
    const float* y   = (const float*)d_in[0];
    const int*   tok = (const int*)d_in[1];
    const float* w1a = (const float*)d_in[2];
    const float* b1a = (const float*)d_in[3];
    const float* w1b = (const float*)d_in[4];
    const float* b1b = (const float*)d_in[5];
    const float* g1  = (const float*)d_in[6];
    const float* be1 = (const float*)d_in[7];
    const float* w2a = (const float*)d_in[8];
    const float* b2a = (const float*)d_in[9];
    const float* w2b = (const float*)d_in[10];
    const float* b2b = (const float*)d_in[11];
    const float* g2  = (const float*)d_in[12];
    const float* be2 = (const float*)d_in[13];
    const float* wl  = (const float*)d_in[14];
    const float* bl  = (const float*)d_in[15];

    float* out = (float*)d_out;

    // workspace layout (halfs)
    const size_t WN   = (size_t)FF * DD * KK;          // 1,769,472 per weight comp
    const size_t SN   = (size_t)BB * PADL * DD;        // 6,303,744
    const size_t H1N  = (size_t)BB * PADL * FF;        // 25,214,976
    _Float16* p = (_Float16*)d_ws;
    _Float16* Wh1a = p;              _Float16* Wl1a = Wh1a + WN;
    _Float16* Wh1b = Wl1a + WN;      _Float16* Wl1b = Wh1b + WN;
    _Float16* Wh2a = Wl1b + WN;      _Float16* Wl2a = Wh2a + WN;
    _Float16* Wh2b = Wl2a + WN;      _Float16* Wl2b = Wh2b + WN;
    _Float16* Shi  = Wl2b + WN;      _Float16* Slo  = Shi + SN;
    _Float16* H1hi = Slo + SN;       _Float16* H1lo = H1hi + H1N;
    int* lns  = (int*)(H1lo + H1N);
    int* csum = lns + BB * LL;

    const int M = BB * LL;                              // 16384

    // 1) weight frag-pack+split, y split, pad-zero for H1
    {
        int n = FF * DD * KK;
        wfrag_k<<<(n + 255) / 256, 256, 0, stream>>>(w1a, Wh1a, Wl1a, FF, DD);
        wfrag_k<<<(n + 255) / 256, 256, 0, stream>>>(w1b, Wh1b, Wl1b, DD, FF);
        wfrag_k<<<(n + 255) / 256, 256, 0, stream>>>(w2a, Wh2a, Wl2a, FF, DD);
        wfrag_k<<<(n + 255) / 256, 256, 0, stream>>>(w2b, Wh2b, Wl2b, DD, FF);
        int ny = BB * PADL * DD;
        ysplit_k<<<(ny + 255) / 256, 256, 0, stream>>>(y, Shi, Slo);
        int np = BB * 2 * FF;
        padzero_k<<<(np + 255) / 256, 256, 0, stream>>>(H1hi, H1lo, FF);
    }
    // 2) four conv-GEMMs (1-D grids, XCD-remapped in-kernel)
    gemm_split<<<(FF / 128) * (M / 128), 256, 0, stream>>>(Shi, Slo, Wh1a, Wl1a, b1a, H1hi, H1lo, DD, FF, 3 * DD, FF / 128);
    gemm_split<<<(DD / 128) * (M / 128), 256, 0, stream>>>(H1hi, H1lo, Wh1b, Wl1b, b1b, Shi, Slo, FF, DD, 3 * FF, DD / 128);
    ln_split_k<<<M, 128, 0, stream>>>(Shi, Slo, g1, be1);
    gemm_split<<<(FF / 128) * (M / 128), 256, 0, stream>>>(Shi, Slo, Wh2a, Wl2a, b2a, H1hi, H1lo, DD, FF, 3 * DD, FF / 128);
    gemm_split<<<(DD / 128) * (M / 128), 256, 0, stream>>>(H1hi, H1lo, Wh2b, Wl2b, b2b, Shi, Slo, FF, DD, 3 * FF, DD / 128);
    // 3) predictor + cumsum + gather
    ln_pred_split_k<<<M, 128, 0, stream>>>(Shi, Slo, g2, be2, wl, bl, tok, lns);
    cumsum_k<<<BB, 1024, 0, stream>>>(lns, csum, out + (size_t)BB * T_OUT * DD);
    {
        long long n = (long long)BB * T_OUT * 96;
        gather_k<<<(int)((n + 255) / 256), 256, 0, stream>>>(y, csum, out);
    }
}